// Round 13
// baseline (267.959 us; speedup 1.0000x reference)
//
#include <hip/hip_runtime.h>
#include <hip/hip_bf16.h>
#include <hip/hip_fp16.h>

// Problem constants: B=2, N=10000, M=320000, QD=KD=HD=256, NUM_HEADS=8, dh=32.
#define DHID 256
#define NHEAD 8
#define BATCH 2
#define PAD 80          // padded bucket capacity; Poisson(32): P(deg>80) ~ 4e-13

typedef _Float16 h8 __attribute__((ext_vector_type(8)));
typedef _Float16 h2 __attribute__((ext_vector_type(2)));
typedef float f4 __attribute__((ext_vector_type(4)));
typedef int i2 __attribute__((ext_vector_type(2)));

// ---- prep: W -> fp16 in LDS-IMAGE order (z<2) + cnt zero (z==2) -----------
// image[ct64][nl*256 + ((c ^ (nl&7))<<3) + j] = W^T[ct64*64+nl][c*8+j], so the
// gemm's B staging is a LINEAR copy (16KB per half-tile) -> global_load_lds.
__global__ __launch_bounds__(256) void prep_kernel(
    const float* __restrict__ Wq, const float* __restrict__ Wk,
    _Float16* __restrict__ Wfq, _Float16* __restrict__ Wfk,
    int* __restrict__ cnt, int N)
{
    if (blockIdx.z == 2) {          // zero histogram bins (64 blocks cover N)
        const int gid = (blockIdx.y * 8 + blockIdx.x) * 256
                      + threadIdx.y * 32 + threadIdx.x;
        if (gid < N) cnt[gid] = 0;
        return;
    }
    const float* W = blockIdx.z ? Wk : Wq;
    _Float16* Wf   = blockIdx.z ? Wfk : Wfq;
    __shared__ float tile[32][33];
    const int tx = threadIdx.x;   // 0..31
    const int ty = threadIdx.y;   // 0..7
    const int n0 = blockIdx.x * 32;
    const int k0 = blockIdx.y * 32;
#pragma unroll
    for (int j = 0; j < 32; j += 8)
        tile[ty + j][tx] = W[(size_t)(k0 + ty + j) * DHID + n0 + tx];
    __syncthreads();
#pragma unroll
    for (int j = 0; j < 32; j += 8) {
        const int n = n0 + ty + j;        // W^T row (output dim)
        const int k = k0 + tx;            // W^T col (input dim)
        const int ct64 = n >> 6, nl = n & 63, c = k >> 3, jj = k & 7;
        Wf[(size_t)ct64 * 16384 + nl * 256 + ((c ^ (nl & 7)) << 3) + jj]
            = (_Float16)tile[tx][ty + j];
    }
}

// ---- MFMA GEMM: fine-grained 16KB async dbuf stages, 3 blocks/CU ----------
// (r12-proven; untouched this round for clean attribution of the edge change)
__global__ __launch_bounds__(256, 3) void gemm_mfma(
    const float* __restrict__ Xq, const float* __restrict__ Xk,
    const _Float16* __restrict__ Wfq, const _Float16* __restrict__ Wfk,
    _Float16* __restrict__ Qh, _Float16* __restrict__ Kh,
    const int* __restrict__ mask, int* __restrict__ cnt, int* __restrict__ sde,
    int nx, int Mrows, int M, int N)
{
    const int t = threadIdx.x;
    if ((int)blockIdx.x >= nx) {                 // ---- scatter side job ----
        const int sb = ((int)blockIdx.x - nx) + (blockIdx.z ? 64 : 0); // 0..127
        for (int e = sb * 256 + t; e < M; e += 128 * 256) {
            int s = mask[e];
            int r = atomicAdd(&cnt[s], 1);
            if (r < PAD) {
                i2 v; v[0] = mask[M + e]; v[1] = e;
                *(i2*)(sde + ((size_t)s * PAD + r) * 2) = v;
            }
        }
        return;
    }

    const float* X     = blockIdx.z ? Xk : Xq;
    const _Float16* Wf = blockIdx.z ? Wfk : Wfq;
    _Float16* C        = blockIdx.z ? Kh : Qh;

    __shared__ _Float16 Bs[2][8192];   // 2 x 16KB double buffer (half-tiles)

    const int lane = t & 63;
    const int wave = t >> 6;
    const int quad = lane >> 4;
    const int l16  = lane & 15;
    const int rowBase = blockIdx.x * 64;
    int arow = rowBase + wave * 16 + l16;
    if (arow >= Mrows) arow = Mrows - 1;   // clamp: OOB tile-rows never stored

    auto stageB = [&](int s, int buf) {
#pragma unroll
        for (int i = 0; i < 4; ++i) {
            const int ci = i * 4 + wave;
            const _Float16* src = Wf + (size_t)s * 8192 + ci * 512 + lane * 8;
            _Float16* dst = &Bs[buf][ci * 512];
#if __has_builtin(__builtin_amdgcn_global_load_lds)
            __builtin_amdgcn_global_load_lds(
                (__attribute__((address_space(1))) void*)src,
                (__attribute__((address_space(3))) void*)dst, 16, 0, 0);
#else
            *(h8*)(dst + lane * 8) = *(const h8*)src;   // fallback: reg copy
#endif
        }
    };

    stageB(0, 0);                       // async: in flight during A staging

    h8 af[8];
#pragma unroll
    for (int kc = 0; kc < 8; ++kc) {
        const float* p = X + (size_t)arow * DHID + (kc * 4 + quad) * 8;
        f4 v0 = *(const f4*)p;
        f4 v1 = *(const f4*)(p + 4);
        h8 hv;
        hv[0]=(_Float16)v0[0]; hv[1]=(_Float16)v0[1]; hv[2]=(_Float16)v0[2]; hv[3]=(_Float16)v0[3];
        hv[4]=(_Float16)v1[0]; hv[5]=(_Float16)v1[1]; hv[6]=(_Float16)v1[2]; hv[7]=(_Float16)v1[3];
        af[kc] = hv;
    }

    __syncthreads();                    // drains vmcnt: stage 0 ready

#pragma unroll
    for (int s = 0; s < 8; ++s) {       // s = ct64*2 + colHalf
        const int cur = s & 1;
        if (s < 7) stageB(s + 1, cur ^ 1);      // async prefetch next half

        const int ct64 = s >> 1;
        const int ch   = s & 1;                  // col half: ct in {2ch, 2ch+1}
        f4 acc[2] = {{0,0,0,0},{0,0,0,0}};
#pragma unroll
        for (int kc = 0; kc < 8; ++kc) {
#pragma unroll
            for (int q = 0; q < 2; ++q) {
                const int ct = ch * 2 + q;
                const int bn = ct * 16 + l16;          // 0..63
                const int bl = bn - ch * 32;           // local row 0..31
                const int bc = (kc * 4 + quad) ^ (bn & 7);
                h8 bfrag = *(const h8*)&Bs[cur][bl * 256 + bc * 8];
                acc[q] = __builtin_amdgcn_mfma_f32_16x16x32_f16(af[kc], bfrag, acc[q], 0, 0, 0);
            }
        }
#pragma unroll
        for (int q = 0; q < 2; ++q) {
            const int ct = ch * 2 + q;
#pragma unroll
            for (int r = 0; r < 4; ++r) {
                int grow = rowBase + wave * 16 + quad * 4 + r;
                if (grow < Mrows) {
                    int bb = grow >= N;
                    int nn = grow - (bb ? N : 0);
                    C[((size_t)nn * 2 + bb) * DHID + ct64 * 64 + ct * 16 + l16]
                        = (_Float16)acc[q][r];
                }
            }
        }
        __syncthreads();   // prefetch drained AFTER compute; buf swap safe
    }
}

// ---- Edge kernel: two srcs/wave + rotated 2-window load pipeline ----------
// r12 PMC: 50% load-issue duty cycle (8 loads drain, then compute with zero
// loads in flight). Rotated 2-window pipeline: issue window it+4's 8 K-loads,
// compute window it, issue it+8, compute it+4 -> waitcnt before compute is a
// partial vmcnt(8), not a drain. All buffers statically indexed (manual
// unroll-by-2). VGPR ~60 <= 64 keeps 8 blocks/CU at 20KB LDS.
__global__ __launch_bounds__(256, 8) void edge_kernel(
    const _Float16* __restrict__ Qh, const _Float16* __restrict__ Kh,
    const int* __restrict__ cnt, const int* __restrict__ sde,
    float* __restrict__ out, int M, int N)
{
    __shared__ _Float16 evs[8][PAD][2][NHEAD];   // 20,480 B
    const int lane   = threadIdx.x & 63;
    const int wave   = threadIdx.x >> 6;
    const int myhalf = lane >> 5;       // which src of the pair
    const int c      = lane & 31;       // 16B chunk within 512B row
    const int h      = c >> 2;          // head of this chunk
    const int slot   = wave * 2 + myhalf;
    const int src    = blockIdx.x * 8 + slot;

    int deg = 0;
    if (src < N) deg = cnt[src];
    if (deg > PAD) deg = PAD;
    const size_t base = (size_t)(src < N ? src : 0) * PAD;

    // preload this half's group entries: lane c holds entries c, c+32, c+64
    int d0 = 0, d1 = 0, d2 = 0, i0 = 0, i1 = 0, i2v = 0;
    if (c < deg)      { i2 v = *(const i2*)(sde + (base + c) * 2);      d0 = v[0]; i0 = v[1]; }
    if (c + 32 < deg) { i2 v = *(const i2*)(sde + (base + c + 32) * 2); d1 = v[0]; i1 = v[1]; }
    if (c + 64 < deg) { i2 v = *(const i2*)(sde + (base + c + 64) * 2); d2 = v[0]; i2v = v[1]; }

    const int degmax = max(deg, __shfl_xor(deg, 32));   // wave-uniform bound
    if (degmax == 0) return;

    const _Float16* Qrow = Qh + (size_t)(src < N ? src : 0) * 2 * DHID;
    const h8 q0 = *(const h8*)(Qrow + c * 8);
    const h8 q1 = *(const h8*)(Qrow + DHID + c * 8);

    float seg0 = 0.f, seg1 = 0.f;       // per-lane = per-head partial (c&3==0)

    // dd for 4 consecutive edge slots starting at 'it' (wave-uniform it)
    auto get_dd = [&](int it, int* dd) {
        const int w = it >> 5;
#pragma unroll
        for (int p = 0; p < 4; ++p) {
            const int srcLane = ((it + p) & 31) + (myhalf << 5);
            const int dv = (w == 0) ? d0 : (w == 1) ? d1 : d2;
            dd[p] = __shfl(dv, srcLane);
        }
    };
    auto load_k = [&](const int* dd, h8* ka, h8* kb) {
#pragma unroll
        for (int p = 0; p < 4; ++p) {
            const _Float16* Krow = Kh + (size_t)dd[p] * 2 * DHID;  // 1KB contig
            ka[p] = *(const h8*)(Krow + c * 8);
            kb[p] = *(const h8*)(Krow + DHID + c * 8);
        }
    };
    auto compute = [&](int it, const h8* ka, const h8* kb) {
#pragma unroll
        for (int p = 0; p < 4; ++p) {
            const int pl = it + p;
            float s0 = 0.f, s1 = 0.f;
#if __has_builtin(__builtin_amdgcn_fdot2)
#pragma unroll
            for (int u = 0; u < 4; ++u) {
                h2 a0, b0, a1, b1;
                a0[0] = q0[2*u];      a0[1] = q0[2*u+1];
                b0[0] = ka[p][2*u];   b0[1] = ka[p][2*u+1];
                a1[0] = q1[2*u];      a1[1] = q1[2*u+1];
                b1[0] = kb[p][2*u];   b1[1] = kb[p][2*u+1];
                s0 = __builtin_amdgcn_fdot2(a0, b0, s0, false);
                s1 = __builtin_amdgcn_fdot2(a1, b1, s1, false);
            }
#else
#pragma unroll
            for (int u = 0; u < 8; ++u) {
                s0 += (float)q0[u] * (float)ka[p][u];
                s1 += (float)q1[u] * (float)kb[p][u];
            }
#endif
            s0 += __shfl_xor(s0, 1); s0 += __shfl_xor(s0, 2);   // 4-lane quad
            s1 += __shfl_xor(s1, 1); s1 += __shfl_xor(s1, 2);   // stays in half
            if ((c & 3) == 0 && pl < deg) {
                _Float16 e0 = (_Float16)__expf(s0 * 0.0625f);   // 1/sqrt(256)
                _Float16 e1 = (_Float16)__expf(s1 * 0.0625f);
                evs[slot][pl][0][h] = e0;
                evs[slot][pl][1][h] = e1;
                seg0 += (float)e0; seg1 += (float)e1;   // quantized: ratio-consistent
            }
        }
    };

    // ---- rotated 2-window pipeline over windows of 4 edge slots ----
    int ddA[4], ddB[4];
    h8 kaA[4], kbA[4], kaB[4], kbB[4];
    get_dd(0, ddA); load_k(ddA, kaA, kbA);
    for (int it = 0; it < degmax; it += 8) {
        if (it + 4 < degmax) { get_dd(it + 4, ddB); load_k(ddB, kaB, kbB); }
        compute(it, kaA, kbA);
        if (it + 8 < degmax) { get_dd(it + 8, ddA); load_k(ddA, kaA, kbA); }
        if (it + 4 < degmax) compute(it + 4, kaB, kbB);
    }

    // per-half, per-head reciprocals (no cross-half combine: different srcs)
    const float r0 = __builtin_amdgcn_rcpf(seg0 + 1e-16f);
    const float r1 = __builtin_amdgcn_rcpf(seg1 + 1e-16f);

    // pass 2: same-lane LDS re-read, normalize, ONE scattered store per elem
    for (int it = 0; it < degmax; it += 4) {
        const int w = it >> 5;
#pragma unroll
        for (int p = 0; p < 4; ++p) {
            const int pl = it + p;
            const int srcLane = (pl & 31) + (myhalf << 5);
            const int ev = (w == 0) ? i0 : (w == 1) ? i1 : i2v;
            const int eid = __shfl(ev, srcLane);
            if ((c & 3) == 0 && pl < deg) {
                float v0 = (float)evs[slot][pl][0][h] * r0;
                float v1 = (float)evs[slot][pl][1][h] * r1;
                __builtin_nontemporal_store(v0, &out[(size_t)eid * NHEAD + h]);
                __builtin_nontemporal_store(v1,
                    &out[(size_t)M * NHEAD + (size_t)eid * NHEAD + h]);
            }
        }
    }
}

extern "C" void kernel_launch(void* const* d_in, const int* in_sizes, int n_in,
                              void* d_out, int out_size, void* d_ws, size_t ws_size,
                              hipStream_t stream) {
    const float* x_q  = (const float*)d_in[0];
    const float* x_k  = (const float*)d_in[1];
    const int*   mask = (const int*)d_in[2];
    const float* w_q  = (const float*)d_in[3];
    const float* w_k  = (const float*)d_in[4];
    float* out = (float*)d_out;

    const int M = in_sizes[2] / 2;                 // 320000
    const int N = in_sizes[0] / (BATCH * DHID);    // 10000
    const int Mrows = BATCH * N;                   // 20000

    // ws: 10.24 + 10.24 + 0.26 + 0.04 + 6.4 = 27.2 MB total
    _Float16* Qh  = (_Float16*)d_ws;               // [N][2][256] interleaved
    _Float16* Kh  = Qh  + (size_t)Mrows * DHID;    // [N][2][256] interleaved
    _Float16* Wfq = Kh  + (size_t)Mrows * DHID;    // LDS-image order, 128KB
    _Float16* Wfk = Wfq + (size_t)DHID * DHID;
    int*      cnt = (int*)(Wfk + (size_t)DHID * DHID);
    int*      sde = cnt + N;                       // [N*PAD] packed {dst, eid}

    // 1) prep: W -> LDS-image fp16 (z<2) + cnt zero (z==2)
    prep_kernel<<<dim3(DHID / 32, DHID / 32, 3), dim3(32, 8), 0, stream>>>(
        w_q, w_k, Wfq, Wfk, cnt, N);

    // 2) GEMM: fine-grained async dbuf (313 x 2) + 128 scatter side blocks
    const int nx = (Mrows + 63) / 64;              // 313
    gemm_mfma<<<dim3(nx + 64, 1, 2), 256, 0, stream>>>(
        x_q, x_k, Wfq, Wfk, Qh, Kh, mask, cnt, sde, nx, Mrows, M, N);

    // 3) edge: two srcs/wave, 2-window pipelined gathers; LDS ev staging
    edge_kernel<<<dim3((N + 7) / 8), 256, 0, stream>>>(
        Qh, Kh, cnt, sde, out, M, N);
}

// Round 14
// 156.680 us; speedup vs baseline: 1.7102x; 1.7102x over previous
//
#include <hip/hip_runtime.h>
#include <hip/hip_bf16.h>
#include <hip/hip_fp16.h>

// Problem constants: B=2, N=10000, M=320000, QD=KD=HD=256, NUM_HEADS=8, dh=32.
#define DHID 256
#define NHEAD 8
#define BATCH 2
#define PAD 80          // padded bucket capacity; Poisson(32): P(deg>80) ~ 4e-13

typedef _Float16 h8 __attribute__((ext_vector_type(8)));
typedef _Float16 h2 __attribute__((ext_vector_type(2)));
typedef float f4 __attribute__((ext_vector_type(4)));
typedef int i2 __attribute__((ext_vector_type(2)));

// ---- prep: W -> fp16 in LDS-IMAGE order (z<2) + cnt zero (z==2) -----------
// image[ct64][nl*256 + ((c ^ (nl&7))<<3) + j] = W^T[ct64*64+nl][c*8+j], so the
// gemm's B staging is a LINEAR copy (16KB per half-tile) -> global_load_lds.
__global__ __launch_bounds__(256) void prep_kernel(
    const float* __restrict__ Wq, const float* __restrict__ Wk,
    _Float16* __restrict__ Wfq, _Float16* __restrict__ Wfk,
    int* __restrict__ cnt, int N)
{
    if (blockIdx.z == 2) {          // zero histogram bins (64 blocks cover N)
        const int gid = (blockIdx.y * 8 + blockIdx.x) * 256
                      + threadIdx.y * 32 + threadIdx.x;
        if (gid < N) cnt[gid] = 0;
        return;
    }
    const float* W = blockIdx.z ? Wk : Wq;
    _Float16* Wf   = blockIdx.z ? Wfk : Wfq;
    __shared__ float tile[32][33];
    const int tx = threadIdx.x;   // 0..31
    const int ty = threadIdx.y;   // 0..7
    const int n0 = blockIdx.x * 32;
    const int k0 = blockIdx.y * 32;
#pragma unroll
    for (int j = 0; j < 32; j += 8)
        tile[ty + j][tx] = W[(size_t)(k0 + ty + j) * DHID + n0 + tx];
    __syncthreads();
#pragma unroll
    for (int j = 0; j < 32; j += 8) {
        const int n = n0 + ty + j;        // W^T row (output dim)
        const int k = k0 + tx;            // W^T col (input dim)
        const int ct64 = n >> 6, nl = n & 63, c = k >> 3, jj = k & 7;
        Wf[(size_t)ct64 * 16384 + nl * 256 + ((c ^ (nl & 7)) << 3) + jj]
            = (_Float16)tile[tx][ty + j];
    }
}

// ---- MFMA GEMM: fine-grained 16KB async dbuf stages, 3 blocks/CU ----------
// (r12-proven form, byte-identical)
__global__ __launch_bounds__(256, 3) void gemm_mfma(
    const float* __restrict__ Xq, const float* __restrict__ Xk,
    const _Float16* __restrict__ Wfq, const _Float16* __restrict__ Wfk,
    _Float16* __restrict__ Qh, _Float16* __restrict__ Kh,
    const int* __restrict__ mask, int* __restrict__ cnt, int* __restrict__ sde,
    int nx, int Mrows, int M, int N)
{
    const int t = threadIdx.x;
    if ((int)blockIdx.x >= nx) {                 // ---- scatter side job ----
        const int sb = ((int)blockIdx.x - nx) + (blockIdx.z ? 64 : 0); // 0..127
        for (int e = sb * 256 + t; e < M; e += 128 * 256) {
            int s = mask[e];
            int r = atomicAdd(&cnt[s], 1);
            if (r < PAD) {
                i2 v; v[0] = mask[M + e]; v[1] = e;
                *(i2*)(sde + ((size_t)s * PAD + r) * 2) = v;
            }
        }
        return;
    }

    const float* X     = blockIdx.z ? Xk : Xq;
    const _Float16* Wf = blockIdx.z ? Wfk : Wfq;
    _Float16* C        = blockIdx.z ? Kh : Qh;

    __shared__ _Float16 Bs[2][8192];   // 2 x 16KB double buffer (half-tiles)

    const int lane = t & 63;
    const int wave = t >> 6;
    const int quad = lane >> 4;
    const int l16  = lane & 15;
    const int rowBase = blockIdx.x * 64;
    int arow = rowBase + wave * 16 + l16;
    if (arow >= Mrows) arow = Mrows - 1;   // clamp: OOB tile-rows never stored

    auto stageB = [&](int s, int buf) {
#pragma unroll
        for (int i = 0; i < 4; ++i) {
            const int ci = i * 4 + wave;
            const _Float16* src = Wf + (size_t)s * 8192 + ci * 512 + lane * 8;
            _Float16* dst = &Bs[buf][ci * 512];
#if __has_builtin(__builtin_amdgcn_global_load_lds)
            __builtin_amdgcn_global_load_lds(
                (__attribute__((address_space(1))) void*)src,
                (__attribute__((address_space(3))) void*)dst, 16, 0, 0);
#else
            *(h8*)(dst + lane * 8) = *(const h8*)src;   // fallback: reg copy
#endif
        }
    };

    stageB(0, 0);                       // async: in flight during A staging

    h8 af[8];
#pragma unroll
    for (int kc = 0; kc < 8; ++kc) {
        const float* p = X + (size_t)arow * DHID + (kc * 4 + quad) * 8;
        f4 v0 = *(const f4*)p;
        f4 v1 = *(const f4*)(p + 4);
        h8 hv;
        hv[0]=(_Float16)v0[0]; hv[1]=(_Float16)v0[1]; hv[2]=(_Float16)v0[2]; hv[3]=(_Float16)v0[3];
        hv[4]=(_Float16)v1[0]; hv[5]=(_Float16)v1[1]; hv[6]=(_Float16)v1[2]; hv[7]=(_Float16)v1[3];
        af[kc] = hv;
    }

    __syncthreads();                    // drains vmcnt: stage 0 ready

#pragma unroll
    for (int s = 0; s < 8; ++s) {       // s = ct64*2 + colHalf
        const int cur = s & 1;
        if (s < 7) stageB(s + 1, cur ^ 1);      // async prefetch next half

        const int ct64 = s >> 1;
        const int ch   = s & 1;                  // col half: ct in {2ch, 2ch+1}
        f4 acc[2] = {{0,0,0,0},{0,0,0,0}};
#pragma unroll
        for (int kc = 0; kc < 8; ++kc) {
#pragma unroll
            for (int q = 0; q < 2; ++q) {
                const int ct = ch * 2 + q;
                const int bn = ct * 16 + l16;          // 0..63
                const int bl = bn - ch * 32;           // local row 0..31
                const int bc = (kc * 4 + quad) ^ (bn & 7);
                h8 bfrag = *(const h8*)&Bs[cur][bl * 256 + bc * 8];
                acc[q] = __builtin_amdgcn_mfma_f32_16x16x32_f16(af[kc], bfrag, acc[q], 0, 0, 0);
            }
        }
#pragma unroll
        for (int q = 0; q < 2; ++q) {
            const int ct = ch * 2 + q;
#pragma unroll
            for (int r = 0; r < 4; ++r) {
                int grow = rowBase + wave * 16 + quad * 4 + r;
                if (grow < Mrows) {
                    int bb = grow >= N;
                    int nn = grow - (bb ? N : 0);
                    C[((size_t)nn * 2 + bb) * DHID + ct64 * 64 + ct * 16 + l16]
                        = (_Float16)acc[q][r];
                }
            }
        }
        __syncthreads();   // prefetch drained AFTER compute; buf swap safe
    }
}

// ---- Edge kernel: TWO src groups per wave (halves), all-resident grid -----
// (r12-proven form, byte-identical: 49.5us, FETCH 108MB, WRITE 20MB.
//  r13's pipeline variant spilled its K-buffers to scratch -> 3x traffic;
//  the pipeline idea is also structurally conserved: in-flight lines =
//  waves x loads x duty, and raising duty raises VGPR which cuts waves.)
__global__ __launch_bounds__(256, 8) void edge_kernel(
    const _Float16* __restrict__ Qh, const _Float16* __restrict__ Kh,
    const int* __restrict__ cnt, const int* __restrict__ sde,
    float* __restrict__ out, int M, int N)
{
    __shared__ _Float16 evs[8][PAD][2][NHEAD];   // 20,480 B
    const int lane   = threadIdx.x & 63;
    const int wave   = threadIdx.x >> 6;
    const int myhalf = lane >> 5;       // which src of the pair
    const int c      = lane & 31;       // 16B chunk within 512B row
    const int h      = c >> 2;          // head of this chunk
    const int slot   = wave * 2 + myhalf;
    const int src    = blockIdx.x * 8 + slot;

    int deg = 0;
    if (src < N) deg = cnt[src];
    if (deg > PAD) deg = PAD;
    const size_t base = (size_t)(src < N ? src : 0) * PAD;

    // preload this half's group entries: lane c holds entries c, c+32, c+64
    int d0 = 0, d1 = 0, d2 = 0, i0 = 0, i1 = 0, i2v = 0;
    if (c < deg)      { i2 v = *(const i2*)(sde + (base + c) * 2);      d0 = v[0]; i0 = v[1]; }
    if (c + 32 < deg) { i2 v = *(const i2*)(sde + (base + c + 32) * 2); d1 = v[0]; i1 = v[1]; }
    if (c + 64 < deg) { i2 v = *(const i2*)(sde + (base + c + 64) * 2); d2 = v[0]; i2v = v[1]; }

    const int degmax = max(deg, __shfl_xor(deg, 32));   // wave-uniform bound
    if (degmax == 0) return;

    const _Float16* Qrow = Qh + (size_t)(src < N ? src : 0) * 2 * DHID;
    const h8 q0 = *(const h8*)(Qrow + c * 8);
    const h8 q1 = *(const h8*)(Qrow + DHID + c * 8);

    float seg0 = 0.f, seg1 = 0.f;       // per-lane = per-head partial (c&3==0)
    for (int it = 0; it < degmax; it += 4) {
        const int w = it >> 5;          // uniform: it%32<=28, p<=3 same window
        int pl[4], dd[4];
#pragma unroll
        for (int p = 0; p < 4; ++p) {
            pl[p] = it + p;
            const int srcLane = ((it + p) & 31) + (myhalf << 5);
            const int dv = (w == 0) ? d0 : (w == 1) ? d1 : d2;
            dd[p] = __shfl(dv, srcLane);
        }
        h8 k0v[4], k1v[4];
#pragma unroll
        for (int p = 0; p < 4; ++p) {
            const _Float16* Krow = Kh + (size_t)dd[p] * 2 * DHID;  // 1KB contig
            k0v[p] = *(const h8*)(Krow + c * 8);
            k1v[p] = *(const h8*)(Krow + DHID + c * 8);
        }
#pragma unroll
        for (int p = 0; p < 4; ++p) {
            float s0 = 0.f, s1 = 0.f;
#if __has_builtin(__builtin_amdgcn_fdot2)
#pragma unroll
            for (int u = 0; u < 4; ++u) {
                h2 a0, b0, a1, b1;
                a0[0] = q0[2*u];      a0[1] = q0[2*u+1];
                b0[0] = k0v[p][2*u];  b0[1] = k0v[p][2*u+1];
                a1[0] = q1[2*u];      a1[1] = q1[2*u+1];
                b1[0] = k1v[p][2*u];  b1[1] = k1v[p][2*u+1];
                s0 = __builtin_amdgcn_fdot2(a0, b0, s0, false);
                s1 = __builtin_amdgcn_fdot2(a1, b1, s1, false);
            }
#else
#pragma unroll
            for (int u = 0; u < 8; ++u) {
                s0 += (float)q0[u] * (float)k0v[p][u];
                s1 += (float)q1[u] * (float)k1v[p][u];
            }
#endif
            s0 += __shfl_xor(s0, 1); s0 += __shfl_xor(s0, 2);   // 4-lane quad
            s1 += __shfl_xor(s1, 1); s1 += __shfl_xor(s1, 2);   // stays in half
            if ((c & 3) == 0 && pl[p] < deg) {
                _Float16 e0 = (_Float16)__expf(s0 * 0.0625f);   // 1/sqrt(256)
                _Float16 e1 = (_Float16)__expf(s1 * 0.0625f);
                evs[slot][pl[p]][0][h] = e0;
                evs[slot][pl[p]][1][h] = e1;
                seg0 += (float)e0; seg1 += (float)e1;   // quantized: ratio-consistent
            }
        }
    }

    // per-half, per-head reciprocals (no cross-half combine: different srcs)
    const float r0 = __builtin_amdgcn_rcpf(seg0 + 1e-16f);
    const float r1 = __builtin_amdgcn_rcpf(seg1 + 1e-16f);

    // pass 2: same-lane LDS re-read, normalize, ONE scattered store per elem
    for (int it = 0; it < degmax; it += 4) {
        const int w = it >> 5;
#pragma unroll
        for (int p = 0; p < 4; ++p) {
            const int pl = it + p;
            const int srcLane = (pl & 31) + (myhalf << 5);
            const int ev = (w == 0) ? i0 : (w == 1) ? i1 : i2v;
            const int eid = __shfl(ev, srcLane);
            if ((c & 3) == 0 && pl < deg) {
                float v0 = (float)evs[slot][pl][0][h] * r0;
                float v1 = (float)evs[slot][pl][1][h] * r1;
                __builtin_nontemporal_store(v0, &out[(size_t)eid * NHEAD + h]);
                __builtin_nontemporal_store(v1,
                    &out[(size_t)M * NHEAD + (size_t)eid * NHEAD + h]);
            }
        }
    }
}

extern "C" void kernel_launch(void* const* d_in, const int* in_sizes, int n_in,
                              void* d_out, int out_size, void* d_ws, size_t ws_size,
                              hipStream_t stream) {
    const float* x_q  = (const float*)d_in[0];
    const float* x_k  = (const float*)d_in[1];
    const int*   mask = (const int*)d_in[2];
    const float* w_q  = (const float*)d_in[3];
    const float* w_k  = (const float*)d_in[4];
    float* out = (float*)d_out;

    const int M = in_sizes[2] / 2;                 // 320000
    const int N = in_sizes[0] / (BATCH * DHID);    // 10000
    const int Mrows = BATCH * N;                   // 20000

    // ws: 10.24 + 10.24 + 0.26 + 0.04 + 6.4 = 27.2 MB total
    _Float16* Qh  = (_Float16*)d_ws;               // [N][2][256] interleaved
    _Float16* Kh  = Qh  + (size_t)Mrows * DHID;    // [N][2][256] interleaved
    _Float16* Wfq = Kh  + (size_t)Mrows * DHID;    // LDS-image order, 128KB
    _Float16* Wfk = Wfq + (size_t)DHID * DHID;
    int*      cnt = (int*)(Wfk + (size_t)DHID * DHID);
    int*      sde = cnt + N;                       // [N*PAD] packed {dst, eid}

    // 1) prep: W -> LDS-image fp16 (z<2) + cnt zero (z==2)
    prep_kernel<<<dim3(DHID / 32, DHID / 32, 3), dim3(32, 8), 0, stream>>>(
        w_q, w_k, Wfq, Wfk, cnt, N);

    // 2) GEMM: fine-grained async dbuf (313 x 2) + 128 scatter side blocks
    const int nx = (Mrows + 63) / 64;              // 313
    gemm_mfma<<<dim3(nx + 64, 1, 2), 256, 0, stream>>>(
        x_q, x_k, Wfq, Wfk, Qh, Kh, mask, cnt, sde, nx, Mrows, M, N);

    // 3) edge: two srcs/wave; LDS ev staging; fused normalize
    edge_kernel<<<dim3((N + 7) / 8), 256, 0, stream>>>(
        Qh, Kh, cnt, sde, out, M, N);
}